// Round 9
// baseline (571.695 us; speedup 1.0000x reference)
//
#include <hip/hip_runtime.h>

// ---------------------------------------------------------------------------
// SelfAttention: x[4,2048,2048] f32; wq,wk,wv,wo [2048,2048] f32 (y = x @ W.T)
//   K0 cvt5:     f32->bf16 for x and all weights
//   K1 qkv_gemm: 256x256-tile 8-phase GEMM -> Q,K [B,H,S,HD], V^T [B,H,HD,S]
//                (Q pre-scaled by 1/sqrt(128)*log2(e): softmax in exp2 domain)
//   K2 attn:     causal flash attention, balanced grid, 72KB LDS (2 blk/CU),
//                half-staged P, defer-max, XCD-swizzled (head-locality)
//   K3 out_gemm: 256x256-tile 8-phase GEMM -> d_out f32
// GEMMs: T1 XCD swizzle (XCD k owns B-panel k) + T2 + T3/T4 + T5.
// ---------------------------------------------------------------------------

#define B_  4
#define S_  2048
#define D_  2048
#define H_  16
#define HD_ 128

typedef __bf16 bf16x8 __attribute__((ext_vector_type(8)));
typedef float  f32x4  __attribute__((ext_vector_type(4)));

#define OFF_XB  0u
#define OFF_WQ  16777216u
#define OFF_WK  20971520u
#define OFF_WV  25165824u
#define OFF_WO  29360128u
#define OFF_QB  33554432u
#define OFF_KB  50331648u
#define OFF_VT  67108864u
#define OFF_AT  83886080u

#define GLOAD_LDS16(gsrc, ldst)                                                   \
  __builtin_amdgcn_global_load_lds(                                               \
      (const __attribute__((address_space(1))) void*)(gsrc),                      \
      (__attribute__((address_space(3))) void*)(ldst), 16, 0, 0)

#define MFMA16(a, b, cacc) __builtin_amdgcn_mfma_f32_16x16x32_bf16(a, b, cacc, 0, 0, 0)

__device__ __forceinline__ unsigned short f2bfu(float f) {
  unsigned u = __float_as_uint(f);
  return (unsigned short)((u + 0x7fffu + ((u >> 16) & 1u)) >> 16);  // RNE
}
__device__ __forceinline__ float bfu2f(unsigned short u) {
  return __uint_as_float(((unsigned)u) << 16);
}

// ---------------------------------------------------------------------------
// K0: convert x + 4 weights to bf16
// ---------------------------------------------------------------------------
__global__ __launch_bounds__(256) void cvt5(const float* __restrict__ x,
                                            const float* __restrict__ wq,
                                            const float* __restrict__ wk,
                                            const float* __restrict__ wv,
                                            const float* __restrict__ wo,
                                            unsigned short* __restrict__ ws) {
  long i = (long)blockIdx.x * 256 + threadIdx.x;
  const float* srcf;
  unsigned short* dst;
  long j;
  if (i < 4194304L)      { srcf = x;  dst = ws + OFF_XB; j = i; }
  else if (i < 5242880L) { srcf = wq; dst = ws + OFF_WQ; j = i - 4194304L; }
  else if (i < 6291456L) { srcf = wk; dst = ws + OFF_WK; j = i - 5242880L; }
  else if (i < 7340032L) { srcf = wv; dst = ws + OFF_WV; j = i - 6291456L; }
  else                   { srcf = wo; dst = ws + OFF_WO; j = i - 7340032L; }
  float4 v = ((const float4*)srcf)[j];
  ushort4 o;
  o.x = f2bfu(v.x); o.y = f2bfu(v.y); o.z = f2bfu(v.z); o.w = f2bfu(v.w);
  ((ushort4*)dst)[j] = o;
}

// ---------------------------------------------------------------------------
// 256x256 8-phase BT-GEMM mainloop (round 3; T2+T3/T4+T5)
// ---------------------------------------------------------------------------
__device__ __forceinline__ void stage_half(const unsigned short* __restrict__ g,
                                           int Kdim, int rowBase, int k0,
                                           unsigned short* lds, int w, int l) {
#pragma unroll
  for (int rr = 0; rr < 2; rr++) {
    int seg = w + rr * 8;
    int row = seg * 8 + (l >> 3);
    int ccol = ((l & 7) ^ (l >> 3)) * 8;
    GLOAD_LDS16(g + (size_t)(rowBase + row) * Kdim + k0 + ccol, lds + seg * 512);
  }
}

__device__ __forceinline__ bf16x8 lds_frag(const unsigned short* half_, int row,
                                           int s, int g) {
  return *(const bf16x8*)((const char*)half_ + row * 128 +
                          ((s * 64 + g * 16) ^ ((row & 7) << 4)));
}

__device__ __forceinline__ void gemm256(const unsigned short* __restrict__ A,
                                        const unsigned short* __restrict__ Bt,
                                        int rowBase, int colBase, int Kdim,
                                        unsigned short* smem, f32x4 (&acc)[8][4]) {
  const int tid = threadIdx.x, w = tid >> 6, l = tid & 63;
  const int wm = w >> 2, wn = w & 3, c = l & 15, g = l >> 4;
  unsigned short* As = smem;
  unsigned short* Bs = smem + 32768;
  const int NT = Kdim / 64;

#pragma unroll
  for (int i = 0; i < 8; i++)
#pragma unroll
    for (int j = 0; j < 4; j++) acc[i][j] = (f32x4){0.f, 0.f, 0.f, 0.f};

  stage_half(A,  Kdim, rowBase,       0,  As + 0 * 8192, w, l);
  stage_half(Bt, Kdim, colBase,       0,  Bs + 0 * 8192, w, l);
  stage_half(Bt, Kdim, colBase + 128, 0,  Bs + 1 * 8192, w, l);
  stage_half(A,  Kdim, rowBase + 128, 0,  As + 1 * 8192, w, l);
  stage_half(A,  Kdim, rowBase,       64, As + 2 * 8192, w, l);
  stage_half(Bt, Kdim, colBase,       64, Bs + 2 * 8192, w, l);
  stage_half(Bt, Kdim, colBase + 128, 64, Bs + 3 * 8192, w, l);
  asm volatile("s_waitcnt vmcnt(6)" ::: "memory");
  asm volatile("s_barrier" ::: "memory");

  bf16x8 aF[4][2], bF[4][2];

  for (int t = 0; t < NT; ++t) {
    const int par = t & 1;
    const unsigned short* A0h = As + (par * 2 + 0) * 8192;
    const unsigned short* A1h = As + (par * 2 + 1) * 8192;
    const unsigned short* B0h = Bs + (par * 2 + 0) * 8192;
    const unsigned short* B1h = Bs + (par * 2 + 1) * 8192;

    // ---- phase 0
#pragma unroll
    for (int m = 0; m < 4; m++) {
      int row = m * 32 + wm * 16 + c;
#pragma unroll
      for (int s = 0; s < 2; s++) aF[m][s] = lds_frag(A0h, row, s, g);
    }
#pragma unroll
    for (int n = 0; n < 2; n++) {
      int row = n * 64 + wn * 16 + c;
#pragma unroll
      for (int s = 0; s < 2; s++) bF[n][s] = lds_frag(B0h, row, s, g);
    }
    if (t + 1 < NT)
      stage_half(A, Kdim, rowBase + 128, (t + 1) * 64,
                 As + (((t + 1) & 1) * 2 + 1) * 8192, w, l);
    asm volatile("s_barrier" ::: "memory");
    __builtin_amdgcn_s_setprio(1);
#pragma unroll
    for (int m = 0; m < 4; m++)
#pragma unroll
      for (int n = 0; n < 2; n++)
#pragma unroll
        for (int s = 0; s < 2; s++) acc[m][n] = MFMA16(aF[m][s], bF[n][s], acc[m][n]);
    __builtin_amdgcn_s_setprio(0);
    asm volatile("s_barrier" ::: "memory");

    // ---- phase 1
#pragma unroll
    for (int n = 0; n < 2; n++) {
      int row = n * 64 + wn * 16 + c;
#pragma unroll
      for (int s = 0; s < 2; s++) bF[2 + n][s] = lds_frag(B1h, row, s, g);
    }
    if (t + 2 < NT)
      stage_half(A, Kdim, rowBase, (t + 2) * 64, As + (par * 2 + 0) * 8192, w, l);
    asm volatile("s_barrier" ::: "memory");
    __builtin_amdgcn_s_setprio(1);
#pragma unroll
    for (int m = 0; m < 4; m++)
#pragma unroll
      for (int n = 0; n < 2; n++)
#pragma unroll
        for (int s = 0; s < 2; s++)
          acc[m][2 + n] = MFMA16(aF[m][s], bF[2 + n][s], acc[m][2 + n]);
    __builtin_amdgcn_s_setprio(0);
    asm volatile("s_barrier" ::: "memory");

    // ---- phase 2
#pragma unroll
    for (int m = 0; m < 4; m++) {
      int row = m * 32 + wm * 16 + c;
#pragma unroll
      for (int s = 0; s < 2; s++) aF[m][s] = lds_frag(A1h, row, s, g);
    }
    if (t + 2 < NT)
      stage_half(Bt, Kdim, colBase, (t + 2) * 64, Bs + (par * 2 + 0) * 8192, w, l);
    asm volatile("s_barrier" ::: "memory");
    __builtin_amdgcn_s_setprio(1);
#pragma unroll
    for (int m = 0; m < 4; m++)
#pragma unroll
      for (int n = 0; n < 2; n++)
#pragma unroll
        for (int s = 0; s < 2; s++)
          acc[4 + m][2 + n] = MFMA16(aF[m][s], bF[2 + n][s], acc[4 + m][2 + n]);
    __builtin_amdgcn_s_setprio(0);
    asm volatile("s_barrier" ::: "memory");

    // ---- phase 3
    if (t + 2 < NT)
      stage_half(Bt, Kdim, colBase + 128, (t + 2) * 64, Bs + (par * 2 + 1) * 8192, w, l);
    asm volatile("s_barrier" ::: "memory");
    __builtin_amdgcn_s_setprio(1);
#pragma unroll
    for (int m = 0; m < 4; m++)
#pragma unroll
      for (int n = 0; n < 2; n++)
#pragma unroll
        for (int s = 0; s < 2; s++)
          acc[4 + m][n] = MFMA16(aF[m][s], bF[n][s], acc[4 + m][n]);
    __builtin_amdgcn_s_setprio(0);
    if (t == NT - 2) asm volatile("s_waitcnt vmcnt(0)" ::: "memory");
    else             asm volatile("s_waitcnt vmcnt(6)" ::: "memory");
    asm volatile("s_barrier" ::: "memory");
  }
}

// ---------------------------------------------------------------------------
// K1: QKV projection.  grid (32, 8, 3), 512 threads.  XCD swizzle: linear id
// o = x + 32y; ty = o&7 (== XCD id), tx = o>>3 -> XCD k keeps B-panel k hot.
// ---------------------------------------------------------------------------
__global__ __launch_bounds__(512, 2) void qkv_gemm(const unsigned short* __restrict__ xb,
                                                   const unsigned short* __restrict__ wqb,
                                                   const unsigned short* __restrict__ wkb,
                                                   const unsigned short* __restrict__ wvb,
                                                   unsigned short* __restrict__ Qb,
                                                   unsigned short* __restrict__ Kb,
                                                   unsigned short* __restrict__ Vtb) {
  __shared__ __align__(16) unsigned short smem[65536];  // 128 KiB
  const int tid = threadIdx.x, w = tid >> 6, l = tid & 63;
  const int wm = w >> 2, wn = w & 3, c = l & 15, g = l >> 4;
  const int mat = blockIdx.z;
  const unsigned short* Bt = (mat == 0) ? wqb : (mat == 1) ? wkb : wvb;
  const int orig = (int)blockIdx.x + 32 * (int)blockIdx.y;
  const int ty = orig & 7, tx = orig >> 3;
  const int rowBase = tx * 256, colBase = ty * 256;

  f32x4 acc[8][4];
  gemm256(xb, Bt, rowBase, colBase, D_, smem, acc);

  const int b = rowBase / S_;
  const int sBase = rowBase & (S_ - 1);

  if (mat < 2) {
    unsigned short* dstb = (mat == 0 ? Qb : Kb);
    const float scale = (mat == 0) ? 0.08838834764831845f * 1.4426950408889634f : 1.0f;
#pragma unroll
    for (int mk = 0; mk < 8; mk++)
#pragma unroll
      for (int nk = 0; nk < 4; nk++) {
        int colT = nk * 64 + wn * 16 + c;
        size_t head = (size_t)(b * H_ + ty * 2 + (colT >> 7));
        int hd = colT & 127;
        unsigned short* dst = dstb + head * S_ * HD_;
#pragma unroll
        for (int r = 0; r < 4; r++) {
          int s = sBase + mk * 32 + wm * 16 + g * 4 + r;
          dst[(size_t)s * HD_ + hd] = f2bfu(acc[mk][nk][r] * scale);
        }
      }
  } else {
#pragma unroll
    for (int mk = 0; mk < 8; mk++)
#pragma unroll
      for (int nk = 0; nk < 4; nk++) {
        int colT = nk * 64 + wn * 16 + c;
        size_t head = (size_t)(b * H_ + ty * 2 + (colT >> 7));
        int hd = colT & 127;
        int s0 = sBase + mk * 32 + wm * 16 + g * 4;
        ushort4 o;
        o.x = f2bfu(acc[mk][nk][0]); o.y = f2bfu(acc[mk][nk][1]);
        o.z = f2bfu(acc[mk][nk][2]); o.w = f2bfu(acc[mk][nk][3]);
        *(ushort4*)&Vtb[(head * HD_ + hd) * S_ + s0] = o;
      }
  }
}

// ---------------------------------------------------------------------------
// K2: causal flash attention.  grid (8, 64) = 512 blocks; XCD swizzle so XCD
// k serves heads [8k,8k+8) (K/V L2 locality).  Each block: q-tiles
// {15-qx, qx} = 34 K-tiles (balanced).  LDS 72KB -> 2 blocks/CU.  Half-staged
// P ([16][32], rows 64B, byte ^= (row&3)<<4).  exp2 softmax + defer-max.
// ---------------------------------------------------------------------------
__global__ __launch_bounds__(512, 4) void attn(const unsigned short* __restrict__ Qb,
                                               const unsigned short* __restrict__ Kb,
                                               const unsigned short* __restrict__ Vtb,
                                               unsigned short* __restrict__ atb) {
  const int orig = (int)blockIdx.x + 8 * (int)blockIdx.y;
  const int xcd = orig & 7, j = orig >> 3;
  const int bh = xcd * 8 + (j & 7);   // XCD k -> heads [8k, 8k+8)
  const int qx = j >> 3;              // 0..7
  const int tid = threadIdx.x, w = tid >> 6, l = tid & 63;
  const int c = l & 15, g = l >> 4;

  __shared__ __align__(16) unsigned short Ks[2][64 * 128];  // 2x16KB
  __shared__ __align__(16) unsigned short Vs[2][128 * 64];  // 2x16KB
  __shared__ __align__(16) unsigned short Ps[8][16 * 32];   // 8KB total

  const unsigned short* Qh = Qb  + (size_t)bh * S_ * HD_;
  const unsigned short* Kh = Kb  + (size_t)bh * S_ * HD_;
  const unsigned short* Vh = Vtb + (size_t)bh * HD_ * S_;

  auto STAGE = [&](int buf, int kt) {
    const char* Kt = (const char*)(Kh + (size_t)kt * 64 * HD_);
#pragma unroll
    for (int rr = 0; rr < 2; rr++) {
      int seg = rr * 8 + w;
      {
        int row = seg * 4 + (l >> 4);
        int cbs = ((l & 15) * 16) ^ ((row & 7) << 4);
        GLOAD_LDS16(Kt + row * 256 + cbs, (char*)Ks[buf] + seg * 1024);
      }
      {
        int row = seg * 8 + (l >> 3);
        int cbs = ((l & 7) * 16) ^ ((row & 7) << 4);
        GLOAD_LDS16((const char*)Vh + (size_t)row * (S_ * 2) + kt * 128 + cbs,
                    (char*)Vs[buf] + seg * 1024);
      }
    }
  };

  for (int half = 0; half < 2; ++half) {
    const int qt = half ? qx : (S_ / 128 - 1) - qx;
    const int q0 = qt * 128;
    const int nkt = 2 * qt + 2;

    bf16x8 qf[4];
    {
      int qrow = q0 + w * 16 + c;
#pragma unroll
      for (int kc = 0; kc < 4; kc++)
        qf[kc] = *(const bf16x8*)&Qh[(size_t)qrow * HD_ + kc * 32 + g * 8];
    }

    f32x4 on[8];
#pragma unroll
    for (int n2 = 0; n2 < 8; n2++) on[n2] = (f32x4){0.f, 0.f, 0.f, 0.f};
    float mrow[4] = {-INFINITY, -INFINITY, -INFINITY, -INFINITY};
    float lrow[4] = {0.f, 0.f, 0.f, 0.f};

    STAGE(0, 0);
    __syncthreads();

    int cur = 0;
    for (int kt = 0; kt < nkt; ++kt) {
      if (kt + 1 < nkt) STAGE(cur ^ 1, kt + 1);

      if (kt * 64 <= q0 + w * 16 + 15) {
        f32x4 sc[4];
#pragma unroll
        for (int n = 0; n < 4; n++) sc[n] = (f32x4){0.f, 0.f, 0.f, 0.f};
        const char* KsB = (const char*)Ks[cur];
        __builtin_amdgcn_s_setprio(1);
#pragma unroll
        for (int n = 0; n < 4; n++) {
          int row = n * 16 + c;
#pragma unroll
          for (int kc = 0; kc < 4; kc++) {
            bf16x8 kf = *(const bf16x8*)(KsB + row * 256 +
                                         ((kc * 64 + g * 16) ^ ((row & 7) << 4)));
            sc[n] = MFMA16(qf[kc], kf, sc[n]);
          }
        }
        __builtin_amdgcn_s_setprio(0);

        if (kt * 64 + 63 > q0 + w * 16) {  // diagonal-overlap: causal mask
#pragma unroll
          for (int n = 0; n < 4; n++)
#pragma unroll
            for (int r = 0; r < 4; r++) {
              int kk = kt * 64 + n * 16 + c;
              int qg = q0 + w * 16 + g * 4 + r;
              if (kk > qg) sc[n][r] = -INFINITY;
            }
        }

        // online softmax (exp2 domain), defer-max THR=11
        float mt[4];
#pragma unroll
        for (int r = 0; r < 4; r++) {
          mt[r] = fmaxf(fmaxf(sc[0][r], sc[1][r]), fmaxf(sc[2][r], sc[3][r]));
#pragma unroll
          for (int d = 1; d < 16; d <<= 1) mt[r] = fmaxf(mt[r], __shfl_xor(mt[r], d));
        }
        bool need = (mt[0] > mrow[0] + 11.f) || (mt[1] > mrow[1] + 11.f) ||
                    (mt[2] > mrow[2] + 11.f) || (mt[3] > mrow[3] + 11.f);
        if (__any(need)) {
#pragma unroll
          for (int r = 0; r < 4; r++) {
            float mn   = fmaxf(mrow[r], mt[r]);
            float corr = exp2f(mrow[r] - mn);
            mrow[r] = mn;
            lrow[r] *= corr;
#pragma unroll
            for (int n2 = 0; n2 < 8; n2++) on[n2][r] *= corr;
          }
        }
        float rs[4] = {0.f, 0.f, 0.f, 0.f};
        unsigned short uu[4][4];
#pragma unroll
        for (int n = 0; n < 4; n++)
#pragma unroll
          for (int r = 0; r < 4; r++) {
            float p = exp2f(sc[n][r] - mrow[r]);
            uu[n][r] = f2bfu(p);
            rs[r] += bfu2f(uu[n][r]);
          }
#pragma unroll
        for (int r = 0; r < 4; r++) {
#pragma unroll
          for (int d = 1; d < 16; d <<= 1) rs[r] += __shfl_xor(rs[r], d);
          lrow[r] += rs[r];
        }

        // PV with half-staged P: per k-half s, write P[16][32] then MFMA
        const char* VsB = (const char*)Vs[cur];
#pragma unroll
        for (int s = 0; s < 2; s++) {
#pragma unroll
          for (int nh = 0; nh < 2; nh++) {
            int n = 2 * s + nh;
#pragma unroll
            for (int r = 0; r < 4; r++) {
              int prow = g * 4 + r;
              int cbyte = ((nh * 16 + c) * 2) ^ ((prow & 3) << 4);
              *(unsigned short*)((char*)Ps[w] + prow * 64 + cbyte) = uu[n][r];
            }
          }
          bf16x8 pa = *(const bf16x8*)((const char*)Ps[w] + c * 64 +
                                       ((g * 16) ^ ((c & 3) << 4)));
          __builtin_amdgcn_s_setprio(1);
#pragma unroll
          for (int n2 = 0; n2 < 8; n2++) {
            int vrow = n2 * 16 + c;
            bf16x8 vb = *(const bf16x8*)(VsB + vrow * 128 +
                                         ((s * 64 + g * 16) ^ ((vrow & 7) << 4)));
            on[n2] = MFMA16(pa, vb, on[n2]);
          }
          __builtin_amdgcn_s_setprio(0);
        }
      }

      __syncthreads();
      cur ^= 1;
    }

    // epilogue: normalize and write attn out [B,S,D] bf16
    const int b = bh >> 4, h = bh & 15;
    float inv[4];
#pragma unroll
    for (int r = 0; r < 4; r++) inv[r] = 1.f / lrow[r];
#pragma unroll
    for (int n2 = 0; n2 < 8; n2++)
#pragma unroll
      for (int r = 0; r < 4; r++) {
        size_t srow = (size_t)(b * S_ + q0 + w * 16 + g * 4 + r);
        atb[srow * D_ + h * HD_ + n2 * 16 + c] = f2bfu(on[n2][r] * inv[r]);
      }
  }
}

// ---------------------------------------------------------------------------
// K3: output projection -> f32.  grid (32, 8), 512 threads, XCD swizzle.
// ---------------------------------------------------------------------------
__global__ __launch_bounds__(512, 2) void out_gemm(const unsigned short* __restrict__ atb,
                                                   const unsigned short* __restrict__ wob,
                                                   float* __restrict__ out) {
  __shared__ __align__(16) unsigned short smem[65536];  // 128 KiB
  const int tid = threadIdx.x, w = tid >> 6, l = tid & 63;
  const int wm = w >> 2, wn = w & 3, c = l & 15, g = l >> 4;
  const int orig = (int)blockIdx.x + 32 * (int)blockIdx.y;
  const int ty = orig & 7, tx = orig >> 3;
  const int rowBase = tx * 256, colBase = ty * 256;

  f32x4 acc[8][4];
  gemm256(atb, wob, rowBase, colBase, D_, smem, acc);

#pragma unroll
  for (int mk = 0; mk < 8; mk++)
#pragma unroll
    for (int nk = 0; nk < 4; nk++) {
      int col = colBase + nk * 64 + wn * 16 + c;
#pragma unroll
      for (int r = 0; r < 4; r++) {
        int row = rowBase + mk * 32 + wm * 16 + g * 4 + r;
        out[(size_t)row * D_ + col] = acc[mk][nk][r];
      }
    }
}

// ---------------------------------------------------------------------------
extern "C" void kernel_launch(void* const* d_in, const int* in_sizes, int n_in,
                              void* d_out, int out_size, void* d_ws, size_t ws_size,
                              hipStream_t stream) {
  const float* x  = (const float*)d_in[0];
  const float* wq = (const float*)d_in[1];
  const float* wk = (const float*)d_in[2];
  const float* wv = (const float*)d_in[3];
  const float* wo = (const float*)d_in[4];
  unsigned short* ws = (unsigned short*)d_ws;
  float* out = (float*)d_out;

  unsigned short* xb  = ws + OFF_XB;
  unsigned short* wqb = ws + OFF_WQ;
  unsigned short* wkb = ws + OFF_WK;
  unsigned short* wvb = ws + OFF_WV;
  unsigned short* wob = ws + OFF_WO;
  unsigned short* Qb  = ws + OFF_QB;
  unsigned short* Kb  = ws + OFF_KB;
  unsigned short* Vtb = ws + OFF_VT;
  unsigned short* atb = ws + OFF_AT;

  hipLaunchKernelGGL(cvt5, dim3(32768), dim3(256), 0, stream, x, wq, wk, wv, wo, ws);
  hipLaunchKernelGGL(qkv_gemm, dim3(32, 8, 3), dim3(512), 0, stream,
                     xb, wqb, wkb, wvb, Qb, Kb, Vtb);
  hipLaunchKernelGGL(attn, dim3(8, 64), dim3(512), 0, stream, Qb, Kb, Vtb, atb);
  hipLaunchKernelGGL(out_gemm, dim3(32, 8), dim3(512), 0, stream, atb, wob, out);
}